// Round 24
// baseline (99.682 us; speedup 1.0000x reference)
//
#include <hip/hip_runtime.h>
#include <stdint.h>

// ---------- problem constants ----------
#define B_DIM 2
#define T_DIM 4096
#define C_DIM 512
#define H_DIM 8
#define D_DIM 64
#define M_DIM (B_DIM * T_DIM)   // 8192

typedef __attribute__((ext_vector_type(8))) short bf16x8;   // MFMA A/B frag (8 bf16)
typedef __attribute__((ext_vector_type(4))) float f32x4;    // MFMA C/D frag
typedef __attribute__((ext_vector_type(4))) short short4v;  // 8B vector

__device__ inline unsigned short f2bf(float f) {
    union { float f; uint32_t u; } v; v.f = f;
    uint32_t r = v.u + 0x7fffu + ((v.u >> 16) & 1u);   // RNE
    return (unsigned short)(r >> 16);
}

__device__ inline uint32_t cvtpk(float a, float b) {
    uint32_t r;
    asm("v_cvt_pk_bf16_f32 %0, %1, %2" : "=v"(r) : "v"(a), "v"(b));
    return r;
}

__device__ inline float fexp2(float x) {
    float r;
    asm("v_exp_f32 %0, %1" : "=v"(r) : "v"(x));
    return r;
}

__device__ inline float bf2f(unsigned short u) {
    union { uint32_t u; float f; } v; v.u = (uint32_t)u << 16; return v.f;
}

#define KCONST 0.1803368801111204f   // 0.125 * log2(e), folded into Q

// ---------- f32 -> bf16 conversion (x) ----------
__global__ __launch_bounds__(256) void cvt_kernel(const float* __restrict__ in,
                                                  unsigned short* __restrict__ out, int n) {
    int i = (blockIdx.x * 256 + threadIdx.x) * 4;
    if (i >= n) return;
    float4 v = *(const float4*)(in + i);
    uint2 o;
    o.x = cvtpk(v.x, v.y);
    o.y = cvtpk(v.z, v.w);
    *(uint2*)(out + i) = o;
}

// ---------- batched f32 -> bf16 for the 4 weight matrices ----------
__global__ __launch_bounds__(256) void cvt_w_kernel(const float* __restrict__ Wq,
                                                    const float* __restrict__ Wk,
                                                    const float* __restrict__ Wv,
                                                    const float* __restrict__ Wo,
                                                    unsigned short* __restrict__ out) {
    const int widx = blockIdx.x >> 8;
    const float* src = (widx == 0) ? Wq : (widx == 1) ? Wk : (widx == 2) ? Wv : Wo;
    const int i = ((blockIdx.x & 255) * 256 + threadIdx.x) * 4;
    float4 v = *(const float4*)(src + i);
    uint2 o;
    o.x = cvtpk(v.x, v.y);
    o.y = cvtpk(v.z, v.w);
    *(uint2*)(out + (size_t)widx * C_DIM * C_DIM + i) = o;
}

// ---------- LDS-staged fused Q/K/V GEMM (r21 pad 40; Q scaled by KCONST) ----------
__global__ __launch_bounds__(256, 2) void gemm_qkv(const unsigned short* __restrict__ A,
                                                   const unsigned short* __restrict__ Wb,
                                                   unsigned short* __restrict__ Qh,
                                                   unsigned short* __restrict__ Kh,
                                                   unsigned short* __restrict__ Vt) {
    const int tid  = threadIdx.x;
    const int wave = tid >> 6;
    const int lane = tid & 63;
    const int g    = lane >> 4;
    const int lr   = lane & 15;
    const int rowB = blockIdx.x * 128;
    const int col0 = blockIdx.y * 128;
    const int z    = blockIdx.z;
    const unsigned short* W = Wb + (size_t)z * C_DIM * C_DIM;

    __shared__ unsigned short As[2][128][40];
    __shared__ unsigned short Bs[2][128][40];

    const int sr = tid >> 1;
    const int sc = (tid & 1) * 16;

    f32x4 acc[2][8];
#pragma unroll
    for (int r = 0; r < 2; ++r)
#pragma unroll
        for (int i = 0; i < 8; ++i) acc[r][i] = (f32x4){0.f, 0.f, 0.f, 0.f};

    const unsigned short* Ag = A + (size_t)(rowB + sr) * C_DIM + sc;
    const unsigned short* Bg = W + (size_t)(col0 + sr) * C_DIM + sc;

    *(bf16x8*)&As[0][sr][sc]     = *(const bf16x8*)(Ag);
    *(bf16x8*)&As[0][sr][sc + 8] = *(const bf16x8*)(Ag + 8);
    *(bf16x8*)&Bs[0][sr][sc]     = *(const bf16x8*)(Bg);
    *(bf16x8*)&Bs[0][sr][sc + 8] = *(const bf16x8*)(Bg + 8);
    __syncthreads();

    int cur = 0;
#pragma unroll 1
    for (int kk = 0; kk < C_DIM; kk += 32) {
        const bool hn = (kk + 32 < C_DIM);
        bf16x8 na0, na1, nb0, nb1;
        if (hn) {
            na0 = *(const bf16x8*)(Ag + kk + 32);
            na1 = *(const bf16x8*)(Ag + kk + 40);
            nb0 = *(const bf16x8*)(Bg + kk + 32);
            nb1 = *(const bf16x8*)(Bg + kk + 40);
        }

        bf16x8 a0 = *(const bf16x8*)&As[cur][wave * 32 + lr][g * 8];
        bf16x8 a1 = *(const bf16x8*)&As[cur][wave * 32 + 16 + lr][g * 8];
#pragma unroll
        for (int nt = 0; nt < 8; ++nt) {
            bf16x8 b = *(const bf16x8*)&Bs[cur][nt * 16 + lr][g * 8];
            acc[0][nt] = __builtin_amdgcn_mfma_f32_16x16x32_bf16(a0, b, acc[0][nt], 0, 0, 0);
            acc[1][nt] = __builtin_amdgcn_mfma_f32_16x16x32_bf16(a1, b, acc[1][nt], 0, 0, 0);
        }

        if (hn) {
            *(bf16x8*)&As[cur ^ 1][sr][sc]     = na0;
            *(bf16x8*)&As[cur ^ 1][sr][sc + 8] = na1;
            *(bf16x8*)&Bs[cur ^ 1][sr][sc]     = nb0;
            *(bf16x8*)&Bs[cur ^ 1][sr][sc + 8] = nb1;
        }
        __syncthreads();
        cur ^= 1;
    }

    const int row0 = rowB + wave * 32;
    unsigned short* Oqk = (z == 0) ? Qh : Kh;
    const float qs = (z == 0) ? KCONST : 1.0f;   // fold softmax scale into Q
#pragma unroll
    for (int ar = 0; ar < 2; ++ar) {
        const int rowb = row0 + ar * 16;
#pragma unroll
        for (int nt = 0; nt < 8; ++nt) {
            const int n = col0 + nt * 16 + lr;
            const int h = n >> 6, d = n & 63;
            if (z < 2) {
#pragma unroll
                for (int j = 0; j < 4; ++j) {
                    int m = rowb + g * 4 + j;
                    int b = m >> 12, t = m & (T_DIM - 1);
                    Oqk[((size_t)(b * H_DIM + h) * T_DIM + t) * D_DIM + d] = f2bf(acc[ar][nt][j] * qs);
                }
            } else {
                int m = rowb + g * 4;
                int b = m >> 12, t = m & (T_DIM - 1);
                int tp = (t & ~31) | (((t >> 2) & 3) << 3) | (((t >> 4) & 1) << 2);
                short4v pack;
#pragma unroll
                for (int j = 0; j < 4; ++j) pack[j] = (short)f2bf(acc[ar][nt][j]);
                *(short4v*)(Vt + ((size_t)(b * H_DIM + h) * D_DIM + d) * T_DIM + tp) = pack;
            }
        }
    }
}

// ---------- merge two pO halves for 16 cols of one (b,h,t) row ----------
__device__ inline void mergeA16(const unsigned short* __restrict__ pO,
                                const float* __restrict__ pl,
                                int rowid, int d, bf16x8* out0, bf16x8* out1) {
    const size_t HS = (size_t)65536 * 64;
    const size_t pb = (size_t)rowid * 64 + d;
    bf16x8 lo0 = *(const bf16x8*)(pO + pb);
    bf16x8 lo1 = *(const bf16x8*)(pO + pb + 8);
    bf16x8 hi0 = *(const bf16x8*)(pO + HS + pb);
    bf16x8 hi1 = *(const bf16x8*)(pO + HS + pb + 8);
    const float linv = 1.0f / (pl[rowid] + pl[65536 + rowid]);
    union { bf16x8 v; uint32_t w[4]; } a, b;
#pragma unroll
    for (int i = 0; i < 4; ++i) {
        a.w[i] = cvtpk((bf2f((unsigned short)lo0[2 * i])     + bf2f((unsigned short)hi0[2 * i]))     * linv,
                       (bf2f((unsigned short)lo0[2 * i + 1]) + bf2f((unsigned short)hi0[2 * i + 1])) * linv);
        b.w[i] = cvtpk((bf2f((unsigned short)lo1[2 * i])     + bf2f((unsigned short)hi1[2 * i]))     * linv,
                       (bf2f((unsigned short)lo1[2 * i + 1]) + bf2f((unsigned short)hi1[2 * i + 1])) * linv);
    }
    *out0 = a.v;
    *out1 = b.v;
}

// ---------- output GEMM with fused partial-merge A-staging (f32 out) ----------
// A = attention output, reconstructed on the fly from pO halves + pl during
// LDS staging (merge kernel + attnb buffer eliminated). Each 16-col staging
// chunk is head-aligned (sc in {0,16}, kk%32==0) -> single (b,h,t) row.
__global__ __launch_bounds__(256, 2) void gemm_out(const unsigned short* __restrict__ pO,
                                                   const float* __restrict__ pl,
                                                   const unsigned short* __restrict__ W,
                                                   float* __restrict__ O) {
    const int tid  = threadIdx.x;
    const int wave = tid >> 6;
    const int lane = tid & 63;
    const int g    = lane >> 4;
    const int lr   = lane & 15;
    const int rowB = blockIdx.x * 128;
    const int col0 = blockIdx.y * 128;

    __shared__ unsigned short As[2][128][40];
    __shared__ unsigned short Bs[2][128][40];

    const int sr = tid >> 1;
    const int sc = (tid & 1) * 16;
    const int m  = rowB + sr;
    const int bb = m >> 12, tt = m & (T_DIM - 1);

    f32x4 acc[2][8];
#pragma unroll
    for (int r = 0; r < 2; ++r)
#pragma unroll
        for (int i = 0; i < 8; ++i) acc[r][i] = (f32x4){0.f, 0.f, 0.f, 0.f};

    const unsigned short* Bg = W + (size_t)(col0 + sr) * C_DIM + sc;

    // prologue: stage k=0..31 (A via merge, B raw)
    {
        const int c = sc;                       // 0 or 16 -> h = 0
        const int rowid = ((bb * 8 + (c >> 6)) << 12) | tt;
        bf16x8 a0, a1;
        mergeA16(pO, pl, rowid, c & 63, &a0, &a1);
        *(bf16x8*)&As[0][sr][sc]     = a0;
        *(bf16x8*)&As[0][sr][sc + 8] = a1;
    }
    *(bf16x8*)&Bs[0][sr][sc]     = *(const bf16x8*)(Bg);
    *(bf16x8*)&Bs[0][sr][sc + 8] = *(const bf16x8*)(Bg + 8);
    __syncthreads();

    int cur = 0;
#pragma unroll 1
    for (int kk = 0; kk < C_DIM; kk += 32) {
        const bool hn = (kk + 32 < C_DIM);
        bf16x8 na0, na1, nb0, nb1;
        if (hn) {
            const int c = kk + 32 + sc;
            const int rowid = ((bb * 8 + (c >> 6)) << 12) | tt;
            mergeA16(pO, pl, rowid, c & 63, &na0, &na1);
            nb0 = *(const bf16x8*)(Bg + kk + 32);
            nb1 = *(const bf16x8*)(Bg + kk + 40);
        }

        bf16x8 a0 = *(const bf16x8*)&As[cur][wave * 32 + lr][g * 8];
        bf16x8 a1 = *(const bf16x8*)&As[cur][wave * 32 + 16 + lr][g * 8];
#pragma unroll
        for (int nt = 0; nt < 8; ++nt) {
            bf16x8 b = *(const bf16x8*)&Bs[cur][nt * 16 + lr][g * 8];
            acc[0][nt] = __builtin_amdgcn_mfma_f32_16x16x32_bf16(a0, b, acc[0][nt], 0, 0, 0);
            acc[1][nt] = __builtin_amdgcn_mfma_f32_16x16x32_bf16(a1, b, acc[1][nt], 0, 0, 0);
        }

        if (hn) {
            *(bf16x8*)&As[cur ^ 1][sr][sc]     = na0;
            *(bf16x8*)&As[cur ^ 1][sr][sc + 8] = na1;
            *(bf16x8*)&Bs[cur ^ 1][sr][sc]     = nb0;
            *(bf16x8*)&Bs[cur ^ 1][sr][sc + 8] = nb1;
        }
        __syncthreads();
        cur ^= 1;
    }

    const int row0 = rowB + wave * 32;
#pragma unroll
    for (int ar = 0; ar < 2; ++ar) {
        const int rowb = row0 + ar * 16;
#pragma unroll
        for (int nt = 0; nt < 8; ++nt) {
            const int n = col0 + nt * 16 + lr;
#pragma unroll
            for (int j = 0; j < 4; ++j) {
                int mm = rowb + g * 4 + j;
                O[(size_t)mm * C_DIM + n] = acc[ar][nt][j];
            }
        }
    }
}

// ---------- LDS-staged attention (r23 exact; KC pre-folded into Q) ----------
__global__ __launch_bounds__(256, 2) void attn_lds(const unsigned short* __restrict__ Qh,
                                                   const unsigned short* __restrict__ Kh,
                                                   const unsigned short* __restrict__ Vt,
                                                   unsigned short* __restrict__ pO,
                                                   float* __restrict__ pl) {
    const int tid  = threadIdx.x;
    const int wave = tid >> 6;
    const int lane = tid & 63;
    const int g    = lane >> 4;
    const int lr   = lane & 15;
    const int srow = (tid >> 3) & 31;
    const int scol = (tid & 7) * 8;
    const int bid  = blockIdx.x;
    const int bh   = bid & 15;
    const int half = (bid >> 4) & 1;
    const int pr   = bid >> 5;           // 0..15

    const unsigned short* Qp = Qh + (size_t)bh * T_DIM * D_DIM;
    const unsigned short* Kp = Kh + (size_t)bh * T_DIM * D_DIM;
    const unsigned short* Vp = Vt + (size_t)bh * D_DIM * T_DIM;

    const short oneb = (short)0x3F80;    // bf16 1.0
    const bf16x8 ones = {oneb, oneb, oneb, oneb, oneb, oneb, oneb, oneb};

    __shared__ unsigned short Kb[2][2][64][72];
    __shared__ unsigned short Vb[2][2][64][72];

#pragma unroll 1
    for (int t = 0; t < 2; ++t) {
        const int qt = t ? (31 - pr) : pr;
        const int qw = qt * 128 + wave * 32;
        const int kvend_w = qw + 32;
        const int kvend_b = qt * 128 + 128;
        const int kvstart = half * 128;

        bf16x8 qf[2][2];
#pragma unroll
        for (int h = 0; h < 2; ++h)
#pragma unroll
            for (int dh = 0; dh < 2; ++dh)
                qf[h][dh] = *(const bf16x8*)(Qp + (size_t)(qw + h * 16 + lr) * D_DIM + dh * 32 + g * 8);

        f32x4 oacc[2][4];
        f32x4 o5[2];
#pragma unroll
        for (int h = 0; h < 2; ++h) {
#pragma unroll
            for (int d0 = 0; d0 < 4; ++d0) oacc[h][d0] = (f32x4){0.f, 0.f, 0.f, 0.f};
            o5[h] = (f32x4){0.f, 0.f, 0.f, 0.f};
        }

#pragma unroll
        for (int s = 0; s < 2; ++s) {
            const int kb = kvstart + s * 64;
            const unsigned short* Ks = Kp + (size_t)(kb + srow) * D_DIM + scol;
            bf16x8 k0 = *(const bf16x8*)(Ks);
            bf16x8 k1 = *(const bf16x8*)(Ks + 32 * D_DIM);
            const unsigned short* Vs = Vp + (size_t)srow * T_DIM + kb + scol;
            bf16x8 v0 = *(const bf16x8*)(Vs);
            bf16x8 v1 = *(const bf16x8*)(Vs + 32 * T_DIM);
            *(bf16x8*)&Kb[0][s][srow][scol]      = k0;
            *(bf16x8*)&Kb[0][s][srow + 32][scol] = k1;
            *(bf16x8*)&Vb[0][s][srow][scol]      = v0;
            *(bf16x8*)&Vb[0][s][srow + 32][scol] = v1;
        }
        __syncthreads();

        int cur = 0;
#pragma unroll 1
        for (int kv0 = kvstart; kv0 < kvend_b; kv0 += 256) {
            const int kvn = kv0 + 256;
            const bool hn = kvn < kvend_b;

            bf16x8 gk[2][2], gv[2][2];
            if (hn) {
#pragma unroll
                for (int s = 0; s < 2; ++s) {
                    const int kb = kvn + s * 64;
                    const unsigned short* Ks = Kp + (size_t)(kb + srow) * D_DIM + scol;
                    gk[s][0] = *(const bf16x8*)(Ks);
                    gk[s][1] = *(const bf16x8*)(Ks + 32 * D_DIM);
                    const unsigned short* Vs = Vp + (size_t)srow * T_DIM + kb + scol;
                    gv[s][0] = *(const bf16x8*)(Vs);
                    gv[s][1] = *(const bf16x8*)(Vs + 32 * T_DIM);
                }
            }

#pragma unroll 1
            for (int sub = 0; sub < 2; ++sub) {
                const int kvu = kv0 + sub * 64;
                if (kvu < kvend_w) {
                    bf16x8 kc8[4][2], vf[2][4];
#pragma unroll
                    for (int i = 0; i < 4; ++i)
#pragma unroll
                        for (int dh = 0; dh < 2; ++dh)
                            kc8[i][dh] = *(const bf16x8*)&Kb[cur][sub][i * 16 + lr][dh * 32 + g * 8];
#pragma unroll
                    for (int kh = 0; kh < 2; ++kh)
#pragma unroll
                        for (int d0 = 0; d0 < 4; ++d0)
                            vf[kh][d0] = *(const bf16x8*)&Vb[cur][sub][d0 * 16 + lr][kh * 32 + g * 8];

                    f32x4 s[2][4];
#pragma unroll
                    for (int h = 0; h < 2; ++h)
#pragma unroll
                        for (int i = 0; i < 4; ++i) s[h][i] = (f32x4){0.f, 0.f, 0.f, 0.f};
#pragma unroll
                    for (int i = 0; i < 4; ++i) {
                        s[0][i] = __builtin_amdgcn_mfma_f32_16x16x32_bf16(kc8[i][0], qf[0][0], s[0][i], 0, 0, 0);
                        s[0][i] = __builtin_amdgcn_mfma_f32_16x16x32_bf16(kc8[i][1], qf[0][1], s[0][i], 0, 0, 0);
                        s[1][i] = __builtin_amdgcn_mfma_f32_16x16x32_bf16(kc8[i][0], qf[1][0], s[1][i], 0, 0, 0);
                        s[1][i] = __builtin_amdgcn_mfma_f32_16x16x32_bf16(kc8[i][1], qf[1][1], s[1][i], 0, 0, 0);
                    }

                    const bool maskit = (kvu + 63 > qw);
#pragma unroll
                    for (int h = 0; h < 2; ++h) {
                        const int qh = qw + h * 16 + lr;
                        float p[16];
                        if (maskit) {
#pragma unroll
                            for (int i = 0; i < 4; ++i)
#pragma unroll
                                for (int j = 0; j < 4; ++j) {
                                    int kva = kvu + i * 16 + g * 4 + j;
                                    float zz = (kva > qh) ? -1e30f : s[h][i][j];
                                    p[i * 4 + j] = fexp2(zz);   // masked -> 0 (KC pre-folded)
                                }
                        } else {
#pragma unroll
                            for (int i = 0; i < 4; ++i)
#pragma unroll
                                for (int j = 0; j < 4; ++j)
                                    p[i * 4 + j] = fexp2(s[h][i][j]);
                        }

                        union { bf16x8 v; uint32_t w[4]; } pf0, pf1;
#pragma unroll
                        for (int w = 0; w < 4; ++w) pf0.w[w] = cvtpk(p[2 * w], p[2 * w + 1]);
#pragma unroll
                        for (int w = 0; w < 4; ++w) pf1.w[w] = cvtpk(p[8 + 2 * w], p[9 + 2 * w]);

#pragma unroll
                        for (int d0 = 0; d0 < 4; ++d0)
                            oacc[h][d0] = __builtin_amdgcn_mfma_f32_16x16x32_bf16(vf[0][d0], pf0.v, oacc[h][d0], 0, 0, 0);
                        o5[h] = __builtin_amdgcn_mfma_f32_16x16x32_bf16(ones, pf0.v, o5[h], 0, 0, 0);
#pragma unroll
                        for (int d0 = 0; d0 < 4; ++d0)
                            oacc[h][d0] = __builtin_amdgcn_mfma_f32_16x16x32_bf16(vf[1][d0], pf1.v, oacc[h][d0], 0, 0, 0);
                        o5[h] = __builtin_amdgcn_mfma_f32_16x16x32_bf16(ones, pf1.v, o5[h], 0, 0, 0);
                    }
                }
            }

            if (hn) {
#pragma unroll
                for (int s = 0; s < 2; ++s) {
                    *(bf16x8*)&Kb[cur ^ 1][s][srow][scol]      = gk[s][0];
                    *(bf16x8*)&Kb[cur ^ 1][s][srow + 32][scol] = gk[s][1];
                    *(bf16x8*)&Vb[cur ^ 1][s][srow][scol]      = gv[s][0];
                    *(bf16x8*)&Vb[cur ^ 1][s][srow + 32][scol] = gv[s][1];
                }
            }
            __syncthreads();
            cur ^= 1;
        }

        const size_t hb = ((size_t)(half * 16 + bh)) * T_DIM;
#pragma unroll
        for (int h = 0; h < 2; ++h) {
            const int row = qw + h * 16 + lr;
            unsigned short* orow = pO + (hb + row) * D_DIM;
#pragma unroll
            for (int d0 = 0; d0 < 4; ++d0) {
                uint2 st;
                st.x = cvtpk(oacc[h][d0][0], oacc[h][d0][1]);
                st.y = cvtpk(oacc[h][d0][2], oacc[h][d0][3]);
                *(uint2*)(orow + d0 * 16 + g * 4) = st;
            }
            if (g == 0) pl[hb + row] = o5[h][0];
        }
        __syncthreads();
    }
}

// ---------- launch ----------
extern "C" void kernel_launch(void* const* d_in, const int* in_sizes, int n_in,
                              void* d_out, int out_size, void* d_ws, size_t ws_size,
                              hipStream_t stream) {
    const float* x  = (const float*)d_in[0];
    const float* Wq = (const float*)d_in[1];
    const float* Wk = (const float*)d_in[2];
    const float* Wv = (const float*)d_in[3];
    const float* Wo = (const float*)d_in[4];

    char* ws = (char*)d_ws;
    unsigned short* xb    = (unsigned short*)(ws + 0);         //  8.4 MB
    unsigned short* Wb    = (unsigned short*)(ws + 8388608);   //  2 MB
    unsigned short* Qh    = (unsigned short*)(ws + 10485760);  //  8.4 MB
    unsigned short* Kh    = (unsigned short*)(ws + 18874368);  //  8.4 MB
    unsigned short* Vt    = (unsigned short*)(ws + 27262976);  //  8.4 MB
    unsigned short* pO    = (unsigned short*)(ws + 44040192);  // 16.8 MB [2][16][4096][64]
    float*          pl    = (float*)         (ws + 60817408);  //  0.5 MB [2][16][4096]

    const int nX = M_DIM * C_DIM;

    cvt_kernel<<<nX / 4 / 256, 256, 0, stream>>>(x, xb, nX);
    cvt_w_kernel<<<1024, 256, 0, stream>>>(Wq, Wk, Wv, Wo, Wb);

    dim3 gq(M_DIM / 128, C_DIM / 128, 3);
    gemm_qkv<<<gq, 256, 0, stream>>>(xb, Wb, Qh, Kh, Vt);

    attn_lds<<<512, 256, 0, stream>>>(Qh, Kh, Vt, pO, pl);

    gemm_out<<<dim3(M_DIM / 128, C_DIM / 128), 256, 0, stream>>>(pO, pl, Wb + 3 * C_DIM * C_DIM, (float*)d_out);
}

// Round 25
// 96.333 us; speedup vs baseline: 1.0348x; 1.0348x over previous
//
#include <hip/hip_runtime.h>
#include <stdint.h>

// ---------- problem constants ----------
#define B_DIM 2
#define T_DIM 4096
#define C_DIM 512
#define H_DIM 8
#define D_DIM 64
#define M_DIM (B_DIM * T_DIM)   // 8192

typedef __attribute__((ext_vector_type(8))) short bf16x8;   // MFMA A/B frag (8 bf16)
typedef __attribute__((ext_vector_type(4))) float f32x4;    // MFMA C/D frag
typedef __attribute__((ext_vector_type(4))) short short4v;  // 8B vector

__device__ inline unsigned short f2bf(float f) {
    union { float f; uint32_t u; } v; v.f = f;
    uint32_t r = v.u + 0x7fffu + ((v.u >> 16) & 1u);   // RNE
    return (unsigned short)(r >> 16);
}

__device__ inline uint32_t cvtpk(float a, float b) {
    uint32_t r;
    asm("v_cvt_pk_bf16_f32 %0, %1, %2" : "=v"(r) : "v"(a), "v"(b));
    return r;
}

__device__ inline float fexp2(float x) {
    float r;
    asm("v_exp_f32 %0, %1" : "=v"(r) : "v"(x));
    return r;
}

__device__ inline float bf2f(unsigned short u) {
    union { uint32_t u; float f; } v; v.u = (uint32_t)u << 16; return v.f;
}

#define KCONST 0.1803368801111204f   // 0.125 * log2(e), folded into Q (r24-proven)

// ---------- f32 -> bf16 conversion (x) ----------
__global__ __launch_bounds__(256) void cvt_kernel(const float* __restrict__ in,
                                                  unsigned short* __restrict__ out, int n) {
    int i = (blockIdx.x * 256 + threadIdx.x) * 4;
    if (i >= n) return;
    float4 v = *(const float4*)(in + i);
    uint2 o;
    o.x = cvtpk(v.x, v.y);
    o.y = cvtpk(v.z, v.w);
    *(uint2*)(out + i) = o;
}

// ---------- batched f32 -> bf16 for the 4 weight matrices ----------
__global__ __launch_bounds__(256) void cvt_w_kernel(const float* __restrict__ Wq,
                                                    const float* __restrict__ Wk,
                                                    const float* __restrict__ Wv,
                                                    const float* __restrict__ Wo,
                                                    unsigned short* __restrict__ out) {
    const int widx = blockIdx.x >> 8;
    const float* src = (widx == 0) ? Wq : (widx == 1) ? Wk : (widx == 2) ? Wv : Wo;
    const int i = ((blockIdx.x & 255) * 256 + threadIdx.x) * 4;
    float4 v = *(const float4*)(src + i);
    uint2 o;
    o.x = cvtpk(v.x, v.y);
    o.y = cvtpk(v.z, v.w);
    *(uint2*)(out + (size_t)widx * C_DIM * C_DIM + i) = o;
}

// ---------- LDS-staged fused Q/K/V GEMM (r21 pad 40; Q scaled by KCONST) ----------
__global__ __launch_bounds__(256, 2) void gemm_qkv(const unsigned short* __restrict__ A,
                                                   const unsigned short* __restrict__ Wb,
                                                   unsigned short* __restrict__ Qh,
                                                   unsigned short* __restrict__ Kh,
                                                   unsigned short* __restrict__ Vt) {
    const int tid  = threadIdx.x;
    const int wave = tid >> 6;
    const int lane = tid & 63;
    const int g    = lane >> 4;
    const int lr   = lane & 15;
    const int rowB = blockIdx.x * 128;
    const int col0 = blockIdx.y * 128;
    const int z    = blockIdx.z;
    const unsigned short* W = Wb + (size_t)z * C_DIM * C_DIM;

    __shared__ unsigned short As[2][128][40];
    __shared__ unsigned short Bs[2][128][40];

    const int sr = tid >> 1;
    const int sc = (tid & 1) * 16;

    f32x4 acc[2][8];
#pragma unroll
    for (int r = 0; r < 2; ++r)
#pragma unroll
        for (int i = 0; i < 8; ++i) acc[r][i] = (f32x4){0.f, 0.f, 0.f, 0.f};

    const unsigned short* Ag = A + (size_t)(rowB + sr) * C_DIM + sc;
    const unsigned short* Bg = W + (size_t)(col0 + sr) * C_DIM + sc;

    *(bf16x8*)&As[0][sr][sc]     = *(const bf16x8*)(Ag);
    *(bf16x8*)&As[0][sr][sc + 8] = *(const bf16x8*)(Ag + 8);
    *(bf16x8*)&Bs[0][sr][sc]     = *(const bf16x8*)(Bg);
    *(bf16x8*)&Bs[0][sr][sc + 8] = *(const bf16x8*)(Bg + 8);
    __syncthreads();

    int cur = 0;
#pragma unroll 1
    for (int kk = 0; kk < C_DIM; kk += 32) {
        const bool hn = (kk + 32 < C_DIM);
        bf16x8 na0, na1, nb0, nb1;
        if (hn) {
            na0 = *(const bf16x8*)(Ag + kk + 32);
            na1 = *(const bf16x8*)(Ag + kk + 40);
            nb0 = *(const bf16x8*)(Bg + kk + 32);
            nb1 = *(const bf16x8*)(Bg + kk + 40);
        }

        bf16x8 a0 = *(const bf16x8*)&As[cur][wave * 32 + lr][g * 8];
        bf16x8 a1 = *(const bf16x8*)&As[cur][wave * 32 + 16 + lr][g * 8];
#pragma unroll
        for (int nt = 0; nt < 8; ++nt) {
            bf16x8 b = *(const bf16x8*)&Bs[cur][nt * 16 + lr][g * 8];
            acc[0][nt] = __builtin_amdgcn_mfma_f32_16x16x32_bf16(a0, b, acc[0][nt], 0, 0, 0);
            acc[1][nt] = __builtin_amdgcn_mfma_f32_16x16x32_bf16(a1, b, acc[1][nt], 0, 0, 0);
        }

        if (hn) {
            *(bf16x8*)&As[cur ^ 1][sr][sc]     = na0;
            *(bf16x8*)&As[cur ^ 1][sr][sc + 8] = na1;
            *(bf16x8*)&Bs[cur ^ 1][sr][sc]     = nb0;
            *(bf16x8*)&Bs[cur ^ 1][sr][sc + 8] = nb1;
        }
        __syncthreads();
        cur ^= 1;
    }

    const int row0 = rowB + wave * 32;
    unsigned short* Oqk = (z == 0) ? Qh : Kh;
    const float qs = (z == 0) ? KCONST : 1.0f;   // fold softmax scale into Q
#pragma unroll
    for (int ar = 0; ar < 2; ++ar) {
        const int rowb = row0 + ar * 16;
#pragma unroll
        for (int nt = 0; nt < 8; ++nt) {
            const int n = col0 + nt * 16 + lr;
            const int h = n >> 6, d = n & 63;
            if (z < 2) {
#pragma unroll
                for (int j = 0; j < 4; ++j) {
                    int m = rowb + g * 4 + j;
                    int b = m >> 12, t = m & (T_DIM - 1);
                    Oqk[((size_t)(b * H_DIM + h) * T_DIM + t) * D_DIM + d] = f2bf(acc[ar][nt][j] * qs);
                }
            } else {
                int m = rowb + g * 4;
                int b = m >> 12, t = m & (T_DIM - 1);
                int tp = (t & ~31) | (((t >> 2) & 3) << 3) | (((t >> 4) & 1) << 2);
                short4v pack;
#pragma unroll
                for (int j = 0; j < 4; ++j) pack[j] = (short)f2bf(acc[ar][nt][j]);
                *(short4v*)(Vt + ((size_t)(b * H_DIM + h) * D_DIM + d) * T_DIM + tp) = pack;
            }
        }
    }
}

// ---------- LDS-staged output GEMM (f32 out) (r23 exact: lean, reads attnb) ----------
__global__ __launch_bounds__(256, 2) void gemm_out(const unsigned short* __restrict__ A,
                                                   const unsigned short* __restrict__ W,
                                                   float* __restrict__ O) {
    const int tid  = threadIdx.x;
    const int wave = tid >> 6;
    const int lane = tid & 63;
    const int g    = lane >> 4;
    const int lr   = lane & 15;
    const int rowB = blockIdx.x * 128;
    const int col0 = blockIdx.y * 128;

    __shared__ unsigned short As[2][128][40];
    __shared__ unsigned short Bs[2][128][40];

    const int sr = tid >> 1;
    const int sc = (tid & 1) * 16;

    f32x4 acc[2][8];
#pragma unroll
    for (int r = 0; r < 2; ++r)
#pragma unroll
        for (int i = 0; i < 8; ++i) acc[r][i] = (f32x4){0.f, 0.f, 0.f, 0.f};

    const unsigned short* Ag = A + (size_t)(rowB + sr) * C_DIM + sc;
    const unsigned short* Bg = W + (size_t)(col0 + sr) * C_DIM + sc;

    *(bf16x8*)&As[0][sr][sc]     = *(const bf16x8*)(Ag);
    *(bf16x8*)&As[0][sr][sc + 8] = *(const bf16x8*)(Ag + 8);
    *(bf16x8*)&Bs[0][sr][sc]     = *(const bf16x8*)(Bg);
    *(bf16x8*)&Bs[0][sr][sc + 8] = *(const bf16x8*)(Bg + 8);
    __syncthreads();

    int cur = 0;
#pragma unroll 1
    for (int kk = 0; kk < C_DIM; kk += 32) {
        const bool hn = (kk + 32 < C_DIM);
        bf16x8 na0, na1, nb0, nb1;
        if (hn) {
            na0 = *(const bf16x8*)(Ag + kk + 32);
            na1 = *(const bf16x8*)(Ag + kk + 40);
            nb0 = *(const bf16x8*)(Bg + kk + 32);
            nb1 = *(const bf16x8*)(Bg + kk + 40);
        }

        bf16x8 a0 = *(const bf16x8*)&As[cur][wave * 32 + lr][g * 8];
        bf16x8 a1 = *(const bf16x8*)&As[cur][wave * 32 + 16 + lr][g * 8];
#pragma unroll
        for (int nt = 0; nt < 8; ++nt) {
            bf16x8 b = *(const bf16x8*)&Bs[cur][nt * 16 + lr][g * 8];
            acc[0][nt] = __builtin_amdgcn_mfma_f32_16x16x32_bf16(a0, b, acc[0][nt], 0, 0, 0);
            acc[1][nt] = __builtin_amdgcn_mfma_f32_16x16x32_bf16(a1, b, acc[1][nt], 0, 0, 0);
        }

        if (hn) {
            *(bf16x8*)&As[cur ^ 1][sr][sc]     = na0;
            *(bf16x8*)&As[cur ^ 1][sr][sc + 8] = na1;
            *(bf16x8*)&Bs[cur ^ 1][sr][sc]     = nb0;
            *(bf16x8*)&Bs[cur ^ 1][sr][sc + 8] = nb1;
        }
        __syncthreads();
        cur ^= 1;
    }

    const int row0 = rowB + wave * 32;
#pragma unroll
    for (int ar = 0; ar < 2; ++ar) {
        const int rowb = row0 + ar * 16;
#pragma unroll
        for (int nt = 0; nt < 8; ++nt) {
            const int n = col0 + nt * 16 + lr;
#pragma unroll
            for (int j = 0; j < 4; ++j) {
                int m = rowb + g * 4 + j;
                O[(size_t)m * C_DIM + n] = acc[ar][nt][j];
            }
        }
    }
}

// ---------- LDS-staged attention (r23 structure; KC pre-folded into Q) ----------
__global__ __launch_bounds__(256, 2) void attn_lds(const unsigned short* __restrict__ Qh,
                                                   const unsigned short* __restrict__ Kh,
                                                   const unsigned short* __restrict__ Vt,
                                                   unsigned short* __restrict__ pO,
                                                   float* __restrict__ pl) {
    const int tid  = threadIdx.x;
    const int wave = tid >> 6;
    const int lane = tid & 63;
    const int g    = lane >> 4;
    const int lr   = lane & 15;
    const int srow = (tid >> 3) & 31;
    const int scol = (tid & 7) * 8;
    const int bid  = blockIdx.x;
    const int bh   = bid & 15;
    const int half = (bid >> 4) & 1;
    const int pr   = bid >> 5;           // 0..15

    const unsigned short* Qp = Qh + (size_t)bh * T_DIM * D_DIM;
    const unsigned short* Kp = Kh + (size_t)bh * T_DIM * D_DIM;
    const unsigned short* Vp = Vt + (size_t)bh * D_DIM * T_DIM;

    const short oneb = (short)0x3F80;    // bf16 1.0
    const bf16x8 ones = {oneb, oneb, oneb, oneb, oneb, oneb, oneb, oneb};

    __shared__ unsigned short Kb[2][2][64][72];
    __shared__ unsigned short Vb[2][2][64][72];

#pragma unroll 1
    for (int t = 0; t < 2; ++t) {
        const int qt = t ? (31 - pr) : pr;
        const int qw = qt * 128 + wave * 32;
        const int kvend_w = qw + 32;
        const int kvend_b = qt * 128 + 128;
        const int kvstart = half * 128;

        bf16x8 qf[2][2];
#pragma unroll
        for (int h = 0; h < 2; ++h)
#pragma unroll
            for (int dh = 0; dh < 2; ++dh)
                qf[h][dh] = *(const bf16x8*)(Qp + (size_t)(qw + h * 16 + lr) * D_DIM + dh * 32 + g * 8);

        f32x4 oacc[2][4];
        f32x4 o5[2];
#pragma unroll
        for (int h = 0; h < 2; ++h) {
#pragma unroll
            for (int d0 = 0; d0 < 4; ++d0) oacc[h][d0] = (f32x4){0.f, 0.f, 0.f, 0.f};
            o5[h] = (f32x4){0.f, 0.f, 0.f, 0.f};
        }

#pragma unroll
        for (int s = 0; s < 2; ++s) {
            const int kb = kvstart + s * 64;
            const unsigned short* Ks = Kp + (size_t)(kb + srow) * D_DIM + scol;
            bf16x8 k0 = *(const bf16x8*)(Ks);
            bf16x8 k1 = *(const bf16x8*)(Ks + 32 * D_DIM);
            const unsigned short* Vs = Vp + (size_t)srow * T_DIM + kb + scol;
            bf16x8 v0 = *(const bf16x8*)(Vs);
            bf16x8 v1 = *(const bf16x8*)(Vs + 32 * T_DIM);
            *(bf16x8*)&Kb[0][s][srow][scol]      = k0;
            *(bf16x8*)&Kb[0][s][srow + 32][scol] = k1;
            *(bf16x8*)&Vb[0][s][srow][scol]      = v0;
            *(bf16x8*)&Vb[0][s][srow + 32][scol] = v1;
        }
        __syncthreads();

        int cur = 0;
#pragma unroll 1
        for (int kv0 = kvstart; kv0 < kvend_b; kv0 += 256) {
            const int kvn = kv0 + 256;
            const bool hn = kvn < kvend_b;

            bf16x8 gk[2][2], gv[2][2];
            if (hn) {
#pragma unroll
                for (int s = 0; s < 2; ++s) {
                    const int kb = kvn + s * 64;
                    const unsigned short* Ks = Kp + (size_t)(kb + srow) * D_DIM + scol;
                    gk[s][0] = *(const bf16x8*)(Ks);
                    gk[s][1] = *(const bf16x8*)(Ks + 32 * D_DIM);
                    const unsigned short* Vs = Vp + (size_t)srow * T_DIM + kb + scol;
                    gv[s][0] = *(const bf16x8*)(Vs);
                    gv[s][1] = *(const bf16x8*)(Vs + 32 * T_DIM);
                }
            }

#pragma unroll 1
            for (int sub = 0; sub < 2; ++sub) {
                const int kvu = kv0 + sub * 64;
                if (kvu < kvend_w) {
                    bf16x8 kc8[4][2], vf[2][4];
#pragma unroll
                    for (int i = 0; i < 4; ++i)
#pragma unroll
                        for (int dh = 0; dh < 2; ++dh)
                            kc8[i][dh] = *(const bf16x8*)&Kb[cur][sub][i * 16 + lr][dh * 32 + g * 8];
#pragma unroll
                    for (int kh = 0; kh < 2; ++kh)
#pragma unroll
                        for (int d0 = 0; d0 < 4; ++d0)
                            vf[kh][d0] = *(const bf16x8*)&Vb[cur][sub][d0 * 16 + lr][kh * 32 + g * 8];

                    f32x4 s[2][4];
#pragma unroll
                    for (int h = 0; h < 2; ++h)
#pragma unroll
                        for (int i = 0; i < 4; ++i) s[h][i] = (f32x4){0.f, 0.f, 0.f, 0.f};
#pragma unroll
                    for (int i = 0; i < 4; ++i) {
                        s[0][i] = __builtin_amdgcn_mfma_f32_16x16x32_bf16(kc8[i][0], qf[0][0], s[0][i], 0, 0, 0);
                        s[0][i] = __builtin_amdgcn_mfma_f32_16x16x32_bf16(kc8[i][1], qf[0][1], s[0][i], 0, 0, 0);
                        s[1][i] = __builtin_amdgcn_mfma_f32_16x16x32_bf16(kc8[i][0], qf[1][0], s[1][i], 0, 0, 0);
                        s[1][i] = __builtin_amdgcn_mfma_f32_16x16x32_bf16(kc8[i][1], qf[1][1], s[1][i], 0, 0, 0);
                    }

                    const bool maskit = (kvu + 63 > qw);
#pragma unroll
                    for (int h = 0; h < 2; ++h) {
                        const int qh = qw + h * 16 + lr;
                        float p[16];
                        if (maskit) {
#pragma unroll
                            for (int i = 0; i < 4; ++i)
#pragma unroll
                                for (int j = 0; j < 4; ++j) {
                                    int kva = kvu + i * 16 + g * 4 + j;
                                    float zz = (kva > qh) ? -1e30f : s[h][i][j];
                                    p[i * 4 + j] = fexp2(zz);   // masked -> 0 (KC pre-folded)
                                }
                        } else {
#pragma unroll
                            for (int i = 0; i < 4; ++i)
#pragma unroll
                                for (int j = 0; j < 4; ++j)
                                    p[i * 4 + j] = fexp2(s[h][i][j]);
                        }

                        union { bf16x8 v; uint32_t w[4]; } pf0, pf1;
#pragma unroll
                        for (int w = 0; w < 4; ++w) pf0.w[w] = cvtpk(p[2 * w], p[2 * w + 1]);
#pragma unroll
                        for (int w = 0; w < 4; ++w) pf1.w[w] = cvtpk(p[8 + 2 * w], p[9 + 2 * w]);

#pragma unroll
                        for (int d0 = 0; d0 < 4; ++d0)
                            oacc[h][d0] = __builtin_amdgcn_mfma_f32_16x16x32_bf16(vf[0][d0], pf0.v, oacc[h][d0], 0, 0, 0);
                        o5[h] = __builtin_amdgcn_mfma_f32_16x16x32_bf16(ones, pf0.v, o5[h], 0, 0, 0);
#pragma unroll
                        for (int d0 = 0; d0 < 4; ++d0)
                            oacc[h][d0] = __builtin_amdgcn_mfma_f32_16x16x32_bf16(vf[1][d0], pf1.v, oacc[h][d0], 0, 0, 0);
                        o5[h] = __builtin_amdgcn_mfma_f32_16x16x32_bf16(ones, pf1.v, o5[h], 0, 0, 0);
                    }
                }
            }

            if (hn) {
#pragma unroll
                for (int s = 0; s < 2; ++s) {
                    *(bf16x8*)&Kb[cur ^ 1][s][srow][scol]      = gk[s][0];
                    *(bf16x8*)&Kb[cur ^ 1][s][srow + 32][scol] = gk[s][1];
                    *(bf16x8*)&Vb[cur ^ 1][s][srow][scol]      = gv[s][0];
                    *(bf16x8*)&Vb[cur ^ 1][s][srow + 32][scol] = gv[s][1];
                }
            }
            __syncthreads();
            cur ^= 1;
        }

        const size_t hb = ((size_t)(half * 16 + bh)) * T_DIM;
#pragma unroll
        for (int h = 0; h < 2; ++h) {
            const int row = qw + h * 16 + lr;
            unsigned short* orow = pO + (hb + row) * D_DIM;
#pragma unroll
            for (int d0 = 0; d0 < 4; ++d0) {
                uint2 st;
                st.x = cvtpk(oacc[h][d0][0], oacc[h][d0][1]);
                st.y = cvtpk(oacc[h][d0][2], oacc[h][d0][3]);
                *(uint2*)(orow + d0 * 16 + g * 4) = st;
            }
            if (g == 0) pl[hb + row] = o5[h][0];
        }
        __syncthreads();
    }
}

// ---------- merge halves, normalize, write attnb (r23-verified) ----------
__global__ __launch_bounds__(256) void attn_merge(const unsigned short* __restrict__ pO,
                                                  const float* __restrict__ pl,
                                                  unsigned short* __restrict__ attnb) {
    const int c = blockIdx.x * 256 + threadIdx.x;
    const int row = c >> 3;
    const int d = (c & 7) * 8;
    const int bh = row >> 12, r = row & 4095;
    const size_t HS = (size_t)16 * T_DIM * D_DIM;

    const size_t pbase = (size_t)row * D_DIM + d;
    bf16x8 a = *(const bf16x8*)(pO + pbase);
    bf16x8 b = *(const bf16x8*)(pO + HS + pbase);
    const float inv = 1.0f / (pl[row] + pl[(HS / D_DIM) + row]);

    union { bf16x8 v; uint32_t w[4]; } o;
#pragma unroll
    for (int i = 0; i < 4; ++i) {
        float e0 = (bf2f((unsigned short)a[2 * i])     + bf2f((unsigned short)b[2 * i]))     * inv;
        float e1 = (bf2f((unsigned short)a[2 * i + 1]) + bf2f((unsigned short)b[2 * i + 1])) * inv;
        o.w[i] = cvtpk(e0, e1);
    }
    const int bb = bh >> 3, hh = bh & 7;
    *(bf16x8*)(attnb + ((size_t)(bb * T_DIM + r)) * C_DIM + hh * D_DIM + d) = o.v;
}

// ---------- launch ----------
extern "C" void kernel_launch(void* const* d_in, const int* in_sizes, int n_in,
                              void* d_out, int out_size, void* d_ws, size_t ws_size,
                              hipStream_t stream) {
    const float* x  = (const float*)d_in[0];
    const float* Wq = (const float*)d_in[1];
    const float* Wk = (const float*)d_in[2];
    const float* Wv = (const float*)d_in[3];
    const float* Wo = (const float*)d_in[4];

    char* ws = (char*)d_ws;
    unsigned short* xb    = (unsigned short*)(ws + 0);         //  8.4 MB
    unsigned short* Wb    = (unsigned short*)(ws + 8388608);   //  2 MB
    unsigned short* Qh    = (unsigned short*)(ws + 10485760);  //  8.4 MB
    unsigned short* Kh    = (unsigned short*)(ws + 18874368);  //  8.4 MB
    unsigned short* Vt    = (unsigned short*)(ws + 27262976);  //  8.4 MB
    unsigned short* attnb = (unsigned short*)(ws + 35651584);  //  8.4 MB
    unsigned short* pO    = (unsigned short*)(ws + 44040192);  // 16.8 MB
    float*          pl    = (float*)         (ws + 60817408);  //  0.5 MB

    const int nX = M_DIM * C_DIM;

    cvt_kernel<<<nX / 4 / 256, 256, 0, stream>>>(x, xb, nX);
    cvt_w_kernel<<<1024, 256, 0, stream>>>(Wq, Wk, Wv, Wo, Wb);

    dim3 gq(M_DIM / 128, C_DIM / 128, 3);
    gemm_qkv<<<gq, 256, 0, stream>>>(xb, Wb, Qh, Kh, Vt);

    attn_lds<<<512, 256, 0, stream>>>(Qh, Kh, Vt, pO, pl);
    attn_merge<<<2048, 256, 0, stream>>>(pO, pl, attnb);

    gemm_out<<<dim3(M_DIM / 128, C_DIM / 128), 256, 0, stream>>>(attnb, Wb + 3 * C_DIM * C_DIM, (float*)d_out);
}